// Round 6
// baseline (778.274 us; speedup 1.0000x reference)
//
#include <hip/hip_runtime.h>
#include <math.h>

typedef unsigned short ushort_t;
typedef __attribute__((ext_vector_type(8))) short short8;
typedef __attribute__((ext_vector_type(4))) float floatx4;

#define VMCNT(n) asm volatile("s_waitcnt vmcnt(" #n ")" ::: "memory")

// fp32 -> bf16 round-to-nearest-even, bit-level (no NaN inputs here)
__device__ inline ushort_t f2bf(float x) {
    union { float f; unsigned int u; } c; c.f = x;
    unsigned int r = (c.u + 0x7fffu + ((c.u >> 16) & 1u)) >> 16;
    return (ushort_t)r;
}

// async global->LDS, 16 B per lane; lds base must be wave-uniform
__device__ __forceinline__ void glds16(const ushort_t* g, ushort_t* l) {
    __builtin_amdgcn_global_load_lds(
        (const __attribute__((address_space(1))) unsigned int*)g,
        (__attribute__((address_space(3))) unsigned int*)l,
        16, 0, 0);
}

// bank-conflict swizzle: XOR 16B-slot bits (4:6) with bits (7:9).
// Involution; valid for 64B-row tiles (pair-of-rows key) and 128B-row tiles.
__device__ __forceinline__ unsigned swzo(unsigned off) {
    return off ^ ((off >> 3) & 0x70u);
}

// ---------------------------------------------------------------------------
// Kernel 0: W [1024,3072] fp32  ->  W_t [3072,1024] bf16  (unchanged, passing)
__global__ __launch_bounds__(256)
void wt_kernel(const float* __restrict__ W, ushort_t* __restrict__ Wt)
{
    __shared__ float tile[64][65];
    const int k0 = blockIdx.x * 64;
    const int n0 = blockIdx.y * 64;
    const int tid = threadIdx.x;
    #pragma unroll
    for (int ii = 0; ii < 16; ++ii) {
        int idx = ii * 256 + tid;
        int r = idx >> 6, c = idx & 63;
        tile[r][c] = W[(size_t)(k0 + r) * 3072 + n0 + c];
    }
    __syncthreads();
    #pragma unroll
    for (int ii = 0; ii < 16; ++ii) {
        int idx = ii * 256 + tid;
        int r = idx >> 6, c = idx & 63;
        Wt[(size_t)(n0 + r) * 1024 + k0 + c] = f2bf(tile[c][r]);
    }
}

// ---------------------------------------------------------------------------
// Kernel 0b: x [B,S,D] fp32 -> xb bf16 (prepass so qkv can glds16 both sides)
__global__ __launch_bounds__(256)
void xcvt(const float* __restrict__ x, ushort_t* __restrict__ xb)
{
    const int i = (blockIdx.x * 256 + threadIdx.x) * 8;   // exact: 16777216 elems
    float4 f0 = *(const float4*)(x + i);
    float4 f1 = *(const float4*)(x + i + 4);
    ushort_t tmp[8] __attribute__((aligned(16)));
    tmp[0]=f2bf(f0.x); tmp[1]=f2bf(f0.y); tmp[2]=f2bf(f0.z); tmp[3]=f2bf(f0.w);
    tmp[4]=f2bf(f1.x); tmp[5]=f2bf(f1.y); tmp[6]=f2bf(f1.z); tmp[7]=f2bf(f1.w);
    *(uint4*)(xb + i) = *(const uint4*)tmp;
}

// ---------------------------------------------------------------------------
// Kernel 1 (fallback, unchanged): qkv projection, reg-staged fp32 A
__global__ __launch_bounds__(256)
void qkv_mfma(const float* __restrict__ x, const ushort_t* __restrict__ Wt,
              const float* __restrict__ bias,
              ushort_t* __restrict__ q, ushort_t* __restrict__ k,
              ushort_t* __restrict__ vt)
{
    __shared__ ushort_t As[128][72];
    __shared__ ushort_t Bs[128][72];
    const int tid = threadIdx.x;
    const int w = tid >> 6, lane = tid & 63;
    const int m = lane & 15, quad = lane >> 4;
    const int col0 = blockIdx.x * 128;
    const int r0   = blockIdx.y * 128;

    floatx4 o[2][8];
    #pragma unroll
    for (int rf = 0; rf < 2; ++rf)
        #pragma unroll
        for (int nf = 0; nf < 8; ++nf)
            o[rf][nf] = (floatx4){0.f, 0.f, 0.f, 0.f};

    for (int kc = 0; kc < 16; ++kc) {
        const int kdim = kc * 64;
        __syncthreads();
        #pragma unroll
        for (int ii = 0; ii < 4; ++ii) {
            int lin = ii * 256 + tid;
            int row = lin >> 3, seg = lin & 7;
            const float* src = x + (size_t)(r0 + row) * 1024 + kdim + seg * 8;
            float4 f0 = *(const float4*)src;
            float4 f1 = *(const float4*)(src + 4);
            ushort_t tmp[8] __attribute__((aligned(16)));
            tmp[0]=f2bf(f0.x); tmp[1]=f2bf(f0.y); tmp[2]=f2bf(f0.z); tmp[3]=f2bf(f0.w);
            tmp[4]=f2bf(f1.x); tmp[5]=f2bf(f1.y); tmp[6]=f2bf(f1.z); tmp[7]=f2bf(f1.w);
            *(uint4*)&As[row][seg * 8] = *(const uint4*)tmp;
        }
        #pragma unroll
        for (int ii = 0; ii < 4; ++ii) {
            int lin = ii * 256 + tid;
            int row = lin >> 3, seg = lin & 7;
            const ushort_t* src = Wt + (size_t)(col0 + row) * 1024 + kdim + seg * 8;
            *(uint4*)&Bs[row][seg * 8] = *(const uint4*)src;
        }
        __syncthreads();
        #pragma unroll
        for (int kk = 0; kk < 2; ++kk) {
            short8 af[2];
            #pragma unroll
            for (int rf = 0; rf < 2; ++rf)
                af[rf] = *(const short8*)&As[w * 32 + rf * 16 + m][kk * 32 + quad * 8];
            #pragma unroll
            for (int nf = 0; nf < 8; ++nf) {
                short8 bf = *(const short8*)&Bs[nf * 16 + m][kk * 32 + quad * 8];
                #pragma unroll
                for (int rf = 0; rf < 2; ++rf)
                    o[rf][nf] = __builtin_amdgcn_mfma_f32_16x16x32_bf16(af[rf], bf, o[rf][nf], 0, 0, 0);
            }
        }
    }

    const int which = col0 >> 10;
    const int dbase = col0 & 1023;
    float bias_v[8];
    #pragma unroll
    for (int nf = 0; nf < 8; ++nf) bias_v[nf] = bias[col0 + nf * 16 + m];

    #pragma unroll
    for (int rf = 0; rf < 2; ++rf) {
        #pragma unroll
        for (int e = 0; e < 4; ++e) {
            const int g = r0 + w * 32 + rf * 16 + quad * 4 + e;
            #pragma unroll
            for (int nf = 0; nf < 8; ++nf) {
                const int c = dbase + nf * 16 + m;
                float val = o[rf][nf][e] + bias_v[nf];
                if (which == 0) {
                    q[(size_t)g * 1024 + c] = f2bf(val * 0.03125f);
                } else if (which == 1) {
                    k[(size_t)g * 1024 + c] = f2bf(val);
                } else {
                    vt[(size_t)(g >> 12) * 4194304 + (size_t)c * 4096 + (g & 4095)] = f2bf(val);
                }
            }
        }
    }
}

// ---------------------------------------------------------------------------
// Kernel 1 v3 (kept): qkv projection, m97-style; V-third epilogue stages the
// output tile in LDS and stores vt as coalesced 16B runs.
__global__ __launch_bounds__(256)
void qkv_mfma2(const ushort_t* __restrict__ xb, const ushort_t* __restrict__ Wt,
               const float* __restrict__ bias,
               ushort_t* __restrict__ q, ushort_t* __restrict__ k,
               ushort_t* __restrict__ vt)
{
    __shared__ __align__(1024) ushort_t smem[2 * 128 * 64];
    ushort_t (*As)[64] = (ushort_t (*)[64])smem;
    ushort_t (*Bs)[64] = (ushort_t (*)[64])(smem + 128 * 64);
    const int tid = threadIdx.x;
    const int w = tid >> 6, lane = tid & 63;
    const int m = lane & 15, quad = lane >> 4;
    const int lx = lane ^ ((lane >> 3) & 7);
    const int sr = lx >> 3, sc = (lx & 7) * 8;
    const int col0 = blockIdx.x * 128;
    const int r0   = blockIdx.y * 128;

    floatx4 o[2][8];
    #pragma unroll
    for (int rf = 0; rf < 2; ++rf)
        #pragma unroll
        for (int nf = 0; nf < 8; ++nf)
            o[rf][nf] = (floatx4){0.f, 0.f, 0.f, 0.f};

    for (int kc = 0; kc < 16; ++kc) {
        const int kdim = kc * 64;
        __syncthreads();
        #pragma unroll
        for (int ii = 0; ii < 4; ++ii) {
            glds16(xb + (size_t)(r0 + w * 32 + ii * 8 + sr) * 1024 + kdim + sc,
                   &As[w * 32 + ii * 8][0]);
            glds16(Wt + (size_t)(col0 + w * 32 + ii * 8 + sr) * 1024 + kdim + sc,
                   &Bs[w * 32 + ii * 8][0]);
        }
        __syncthreads();
        #pragma unroll
        for (int kk = 0; kk < 2; ++kk) {
            short8 af[2];
            #pragma unroll
            for (int rf = 0; rf < 2; ++rf)
                af[rf] = *(const short8*)((const char*)As +
                          swzo((unsigned)((w * 32 + rf * 16 + m) * 128 + kk * 64 + quad * 16)));
            #pragma unroll
            for (int nf = 0; nf < 8; ++nf) {
                short8 bf = *(const short8*)((const char*)Bs +
                          swzo((unsigned)((nf * 16 + m) * 128 + kk * 64 + quad * 16)));
                #pragma unroll
                for (int rf = 0; rf < 2; ++rf)
                    o[rf][nf] = __builtin_amdgcn_mfma_f32_16x16x32_bf16(af[rf], bf, o[rf][nf], 0, 0, 0);
            }
        }
    }

    const int which = col0 >> 10;
    const int dbase = col0 & 1023;
    float bias_v[8];
    #pragma unroll
    for (int nf = 0; nf < 8; ++nf) bias_v[nf] = bias[col0 + nf * 16 + m];

    if (which == 2) {
        // transpose-store vt: stage [64 cols][128 rows] in LDS, store 16B runs
        const size_t voffb = (size_t)(r0 >> 12) * 4194304;
        const int grow0 = r0 & 4095;
        ushort_t (*T)[136] = (ushort_t (*)[136])smem;
        #pragma unroll
        for (int p = 0; p < 2; ++p) {
            __syncthreads();   // T region free (MFMA reads / prev-pass stores done)
            #pragma unroll
            for (int rf = 0; rf < 2; ++rf)
                #pragma unroll
                for (int e = 0; e < 4; ++e) {
                    const int row = w * 32 + rf * 16 + quad * 4 + e;
                    #pragma unroll
                    for (int nn = 0; nn < 4; ++nn) {
                        const int nf = p * 4 + nn;
                        T[nn * 16 + m][row] = f2bf(o[rf][nf][e] + bias_v[nf]);
                    }
                }
            __syncthreads();
            #pragma unroll
            for (int ii = 0; ii < 4; ++ii) {
                int idx = ii * 256 + tid;
                int c = idx >> 4, seg = idx & 15;
                *(uint4*)&vt[voffb + (size_t)(dbase + p * 64 + c) * 4096 + grow0 + seg * 8]
                    = *(const uint4*)&T[c][seg * 8];
            }
        }
    } else {
        #pragma unroll
        for (int rf = 0; rf < 2; ++rf) {
            #pragma unroll
            for (int e = 0; e < 4; ++e) {
                const int g = r0 + w * 32 + rf * 16 + quad * 4 + e;
                #pragma unroll
                for (int nf = 0; nf < 8; ++nf) {
                    const int c = dbase + nf * 16 + m;
                    float val = o[rf][nf][e] + bias_v[nf];
                    if (which == 0) {
                        q[(size_t)g * 1024 + c] = f2bf(val * 0.03125f);
                    } else {
                        k[(size_t)g * 1024 + c] = f2bf(val);
                    }
                }
            }
        }
    }
}

// ---------------------------------------------------------------------------
// Kernel 2 v10: round-5 v9 (swapped-S + XCD swizzle, 476us) with ONE change:
// S-phase kc widened 32 -> 64 dims per step. Halves S barriers (512->256 per
// block); each phase now 16 ds_reads + 32 MFMA between syncs. Double-buffered
// Qs/Ks with prefetch issued POST-barrier (race-safe: the other buffer's
// readers all passed that barrier) and VMCNT(0) at phase end (loads get the
// full ~500-cyc compute window; L2-resident post-swizzle). Q/K LDS tiles are
// 128B rows; staging lane split + swzo offsets use the 128B-row form already
// verified in qkv_mfma2. exp / PV / finalize byte-identical to round 5.
__global__ __launch_bounds__(512, 2)
void fused_attn(const ushort_t* __restrict__ q, const ushort_t* __restrict__ kb_,
                const ushort_t* __restrict__ vt, float* __restrict__ out)
{
    // LDS map (163840 B = 160 KiB exactly):
    //   [0,32768)        Qs[2][128][64]   -- aliased by Pls
    //   [32768,98304)    Ks[2][256][64]   -- aliased by Pls (upper part free)
    //   [0,67584)        Pls[128][264]    (stride 132 words == 4 mod 32)
    //   [67584,69632)    redL[128][4]     (finalize only; Qs/Ks dead then)
    //   [98304,163840)   Vs[2][512][32]
    __shared__ __align__(1024) unsigned char lds[163840];
    ushort_t (*Qs)[128][64] = (ushort_t(*)[128][64])(lds);
    ushort_t (*Ks)[256][64] = (ushort_t(*)[256][64])(lds + 32768);
    ushort_t (*Pls)[264]    = (ushort_t(*)[264])(lds);
    ushort_t (*Vs)[512][32] = (ushort_t(*)[512][32])(lds + 98304);
    float    (*redL)[4]     = (float(*)[4])(lds + 67584);

    const int tid  = threadIdx.x;
    const int w    = tid >> 6, lane = tid & 63;
    const int m    = lane & 15, quad = lane >> 4;
    const int wr   = w & 1, wc = w >> 1;
    // staging source lane splits (1024B region): 64B rows (V) and 128B rows (Q/K)
    const int lx   = lane ^ ((lane >> 3) & 7);
    const int lr   = lx >> 2, lc  = (lx & 3) * 8;
    const int lrA  = lx >> 3, lcA = (lx & 7) * 8;
    // XCD-aware decode of the 1-D grid (bijective with bid=(n>>1)*8+2b+(n&1))
    const int bid  = blockIdx.x;
    const int b    = (bid & 7) >> 1;
    const int n    = ((bid >> 3) << 1) | (bid & 1);
    const int n0x  = (n >> 5) * 512;
    const int r0   = (n & 31) * 128;
    const size_t qoff = (size_t)b * 4096 * 1024;
    const size_t voff = (size_t)b * 4194304;

    // hoisted swizzled read offsets (bytes, within a tile)
    unsigned qof[4][2], kof[4][2], vof[8];
    #pragma unroll
    for (int i = 0; i < 4; ++i)
        #pragma unroll
        for (int ks = 0; ks < 2; ++ks)
            qof[i][ks] = swzo((unsigned)((wr * 64 + i * 16 + m) * 128 + ks * 64 + quad * 16));
    #pragma unroll
    for (int j = 0; j < 4; ++j)
        #pragma unroll
        for (int ks = 0; ks < 2; ++ks)
            kof[j][ks] = swzo((unsigned)((wc * 64 + j * 16 + m) * 128 + ks * 64 + quad * 16));
    #pragma unroll
    for (int j = 0; j < 8; ++j)
        vof[j] = swzo((unsigned)((wc * 128 + j * 16 + m) * 64 + quad * 16));

    // hoisted glds source row bases (128B-row lane split for Q/K)
    const ushort_t* qsrc = q   + qoff + (size_t)(r0 + w * 16 + lrA) * 1024 + lcA;
    const ushort_t* ksrc = kb_ + qoff + (size_t)(w * 32 + lrA) * 1024 + lcA;

    floatx4 o[4][8];
    #pragma unroll
    for (int i = 0; i < 4; ++i)
        #pragma unroll
        for (int j = 0; j < 8; ++j)
            o[i][j] = (floatx4){0.f, 0.f, 0.f, 0.f};
    float lsum[4] = {};

    for (int kt = 0; kt < 16; ++kt) {
        const int kbase = kt * 256;
        const ushort_t* kptr = ksrc + (size_t)kbase * 1024;

        floatx4 s[4][4];   // s[j][i]: S^T fragment, K-block j x Q-block i
        #pragma unroll
        for (int j = 0; j < 4; ++j)
            #pragma unroll
            for (int i = 0; i < 4; ++i)
                s[j][i] = (floatx4){0.f, 0.f, 0.f, 0.f};

        // ---- S = Q K^T over 1024 dims, kc = 64-dim steps, double-buffered ----
        // prologue: stage kc=0 into buf 0 (safe: prev kt ended on full barrier)
        #pragma unroll
        for (int ii = 0; ii < 2; ++ii)
            glds16(qsrc + ii * 8192, &Qs[0][w * 16 + ii * 8][0]);
        #pragma unroll
        for (int ii = 0; ii < 4; ++ii)
            glds16(kptr + ii * 8192, &Ks[0][w * 32 + ii * 8][0]);
        VMCNT(0);
        __builtin_amdgcn_s_barrier();
        __builtin_amdgcn_sched_barrier(0);
        for (int kc = 0; kc < 16; ++kc) {
            const int cur = kc & 1;
            if (kc < 15) {
                // post-barrier prefetch into the other buffer: its readers
                // (step kc-1) all passed the barrier we just crossed
                const int kd = (kc + 1) * 64;
                #pragma unroll
                for (int ii = 0; ii < 2; ++ii)
                    glds16(qsrc + ii * 8192 + kd, &Qs[cur ^ 1][w * 16 + ii * 8][0]);
                #pragma unroll
                for (int ii = 0; ii < 4; ++ii)
                    glds16(kptr + ii * 8192 + kd, &Ks[cur ^ 1][w * 32 + ii * 8][0]);
            }
            short8 af[4][2], bf[4][2];
            #pragma unroll
            for (int i = 0; i < 4; ++i)
                #pragma unroll
                for (int ks = 0; ks < 2; ++ks)
                    af[i][ks] = *(const short8*)((const char*)Qs[cur] + qof[i][ks]);
            #pragma unroll
            for (int j = 0; j < 4; ++j)
                #pragma unroll
                for (int ks = 0; ks < 2; ++ks)
                    bf[j][ks] = *(const short8*)((const char*)Ks[cur] + kof[j][ks]);
            __builtin_amdgcn_s_setprio(1);
            #pragma unroll
            for (int ks = 0; ks < 2; ++ks)
                #pragma unroll
                for (int j = 0; j < 4; ++j)
                    #pragma unroll
                    for (int i = 0; i < 4; ++i)
                        s[j][i] = __builtin_amdgcn_mfma_f32_16x16x32_bf16(bf[j][ks], af[i][ks], s[j][i], 0, 0, 0);
            __builtin_amdgcn_s_setprio(0);
            // drain the 6 prefetch loads (issued ~500 cyc ago) + resync
            VMCNT(0);
            __builtin_amdgcn_s_barrier();
            __builtin_amdgcn_sched_barrier(0);
        }
        // loop exits on a full barrier with vmem drained: Pls writes safe now

        // ---- exp -> Pls, packed b64 writes (4 consecutive key-cols per lane) ----
        #pragma unroll
        for (int i = 0; i < 4; ++i)
            #pragma unroll
            for (int j = 0; j < 4; ++j) {
                float p0 = __expf(s[j][i][0]);
                float p1 = __expf(s[j][i][1]);
                float p2 = __expf(s[j][i][2]);
                float p3 = __expf(s[j][i][3]);
                lsum[i] += (p0 + p1) + (p2 + p3);
                unsigned lo = (unsigned)f2bf(p0) | ((unsigned)f2bf(p1) << 16);
                unsigned hi = (unsigned)f2bf(p2) | ((unsigned)f2bf(p3) << 16);
                *(uint2*)&Pls[wr * 64 + i * 16 + m][wc * 64 + j * 16 + quad * 4] =
                    (uint2){lo, hi};
            }

        // ---- V(0) staging (after exp, before the barrier) ----
        {
            #pragma unroll
            for (int i = 0; i < 4; ++i)
                glds16(vt + voff + (size_t)(n0x + w * 64 + i * 16 + lr) * 4096 + kbase + lc,
                       &Vs[0][w * 64 + i * 16][0]);
        }
        __syncthreads();   // Pls visible to all waves + V chunk 0 ready

        // ---- O += P V, vc = 32-key chunks, Vs double-buffered (drain style) ----
        for (int vc = 0; vc < 8; ++vc) {
            const int p = vc & 1;
            if (vc < 7) {
                const int kd = kbase + (vc + 1) * 32;
                #pragma unroll
                for (int i = 0; i < 4; ++i)
                    glds16(vt + voff + (size_t)(n0x + w * 64 + i * 16 + lr) * 4096 + kd + lc,
                           &Vs[p ^ 1][w * 64 + i * 16][0]);
            }
            short8 ap[4], bv[8];
            #pragma unroll
            for (int i = 0; i < 4; ++i)
                ap[i] = *(const short8*)&Pls[wr * 64 + i * 16 + m][vc * 32 + quad * 8];
            #pragma unroll
            for (int j = 0; j < 8; ++j)
                bv[j] = *(const short8*)((const char*)Vs[p] + vof[j]);
            __builtin_amdgcn_s_setprio(1);
            #pragma unroll
            for (int i = 0; i < 4; ++i)
                #pragma unroll
                for (int j = 0; j < 8; ++j)
                    o[i][j] = __builtin_amdgcn_mfma_f32_16x16x32_bf16(ap[i], bv[j], o[i][j], 0, 0, 0);
            __builtin_amdgcn_s_setprio(0);
            __syncthreads();   // Vs buf p free for vc+2; after vc=7: Pls/Qs free for next kt
        }
    }

    // ---- finalize: lane holds rowsum partial for row i*16+m over its 16 cols;
    //      reduce over the quad axis (2 shuffles), combine col-quarters ----
    #pragma unroll
    for (int i = 0; i < 4; ++i) {
        float l = lsum[i];
        l += __shfl_xor(l, 16);
        l += __shfl_xor(l, 32);
        if (quad == 0) redL[wr * 64 + i * 16 + m][wc] = l;
    }
    __syncthreads();
    #pragma unroll
    for (int i = 0; i < 4; ++i)
        #pragma unroll
        for (int e = 0; e < 4; ++e) {
            const int row = wr * 64 + i * 16 + quad * 4 + e;
            const float inv = 1.0f / (redL[row][0] + redL[row][1] + redL[row][2] + redL[row][3]);
            const int g = b * 4096 + r0 + row;
            #pragma unroll
            for (int j = 0; j < 8; ++j)
                out[(size_t)g * 1024 + n0x + wc * 128 + j * 16 + m] = o[i][j][e] * inv;
        }
}

// ---------------------------------------------------------------------------
extern "C" void kernel_launch(void* const* d_in, const int* in_sizes, int n_in,
                              void* d_out, int out_size, void* d_ws, size_t ws_size,
                              hipStream_t stream)
{
    const float* x    = (const float*)d_in[0];
    const float* W    = (const float*)d_in[1];
    const float* bias = (const float*)d_in[2];
    float* out = (float*)d_out;

    const size_t SZQ  = (size_t)4 * 4096 * 1024 * 2;     // 32 MiB each
    const size_t SZWT = (size_t)3072 * 1024 * 2;         // 6 MiB
    const size_t SZXB = (size_t)4 * 4096 * 1024 * 2;     // 32 MiB (bf16 x)
    const size_t NEED  = 3 * SZQ + SZWT;
    const size_t NEED2 = NEED + SZXB;
    if (ws_size < NEED) return;

    ushort_t* q  = (ushort_t*)d_ws;
    ushort_t* k  = (ushort_t*)((char*)d_ws + SZQ);
    ushort_t* vt = (ushort_t*)((char*)d_ws + 2 * SZQ);
    ushort_t* Wt = (ushort_t*)((char*)d_ws + 3 * SZQ);
    ushort_t* xb = (ushort_t*)((char*)d_ws + NEED);

    wt_kernel <<<dim3(16, 48),   256, 0, stream>>>(W, Wt);
    if (ws_size >= NEED2) {
        xcvt      <<<dim3(8192),    256, 0, stream>>>(x, xb);
        qkv_mfma2 <<<dim3(24, 128), 256, 0, stream>>>(xb, Wt, bias, q, k, vt);
    } else {
        qkv_mfma  <<<dim3(24, 128), 256, 0, stream>>>(x, Wt, bias, q, k, vt);
    }
    fused_attn<<<dim3(256), 512, 0, stream>>>(q, k, vt, out);
}